// Round 13
// baseline (101.737 us; speedup 1.0000x reference)
//
#include <hip/hip_runtime.h>

#define NMODELS 128
#define SZ_IN 256
#define SZ_OUT 256
#define CHUNK 16
#define MAXLIST 192   // Poisson(32)/model; P(cnt>192) ~ 0 (clamped for safety)
#define LDSK 264      // bf16 A-row stride: 2-way bank alias (free)
#define NT 512        // 8 waves = 8 n-tiles of the block's 128-col half
#define FRAGSTRIDE 520  // shorts per fragment slot: 512 data + 8 stagger (banks)

typedef __attribute__((ext_vector_type(4))) float f32x4;
typedef __attribute__((ext_vector_type(8))) short bf16x8;
typedef __attribute__((ext_vector_type(4))) short s16x4;

// fp32 -> bf16 RNE (bit pattern)
__device__ __forceinline__ short f2bf(float f) {
  union { float f; unsigned u; } v;
  v.f = f;
  const unsigned r = v.u + 0x7FFFu + ((v.u >> 16) & 1u);
  return (short)(r >> 16);
}

// R13 = R12's kernel, UNCHANGED, launched TWICE (timing diagnostic):
// dur13 - dur12 = kernel duration (L2-warm), independent of the unknown
// harness overhead constant. Kernel is idempotent (deterministic list,
// same stores both runs) -> graph-safe, correctness unchanged.
__global__ __launch_bounds__(NT, 2) void linmulti_v13(
    const float* __restrict__ inp, const int* __restrict__ ids,
    const float* __restrict__ wlut, const float* __restrict__ blut,
    float* __restrict__ out, int B) {
  const int ch = blockIdx.x;  // 0..1 (128-col half)
  const int m = blockIdx.y;   // 0..127
  const int tid = threadIdx.x;
  const int lane = tid & 63;
  const int wv = tid >> 6;   // 0..7 = this wave's n-tile
  const int q = lane >> 4;
  const int n16 = lane & 15;
  const int col = ch * 128 + wv * 16 + n16;

  __shared__ short Wfrag[64 * FRAGSTRIDE];  // 66,560 B; reused as A-tile later
  __shared__ int list[MAXLIST];
  __shared__ int wcnt[8][8];
  short* As = Wfrag;  // A-tile alias (needs 16*LDSK = 4224 shorts)

  // ---- ids loads first (8 coalesced dwords/lane) ----
  int myid[8];
#pragma unroll
  for (int v = 0; v < 8; ++v) {
    const int b = v * NT + tid;
    myid[v] = (b < B) ? ids[b] : -1;
  }

  // ---- W slice, coalesced: 16 f32x4/thread, 512 B row segments ----
  const float* __restrict__ Wb = wlut + (size_t)m * (SZ_IN * SZ_OUT) + ch * 128;
  f32x4 wraw[16];
#pragma unroll
  for (int v = 0; v < 16; ++v) {
    const int e4 = v * NT + tid;       // [0, 8192)
    const int r = e4 >> 5;             // k-row 0..255
    const int c4 = e4 & 31;            // f32x4 within the 128-col row
    wraw[v] = *(const f32x4*)(Wb + (size_t)r * SZ_OUT + c4 * 4);
  }

  // ---- deterministic member list (ballot scan, ordered by b) ----
#pragma unroll
  for (int v = 0; v < 8; ++v) {
    const unsigned long long mk = __ballot(myid[v] == m);
    if (lane == 0) wcnt[v][wv] = __popcll(mk);
  }
  __syncthreads();
  int run = 0;
#pragma unroll
  for (int v = 0; v < 8; ++v) {
    int wbase = run;
    for (int w = 0; w < wv; ++w) wbase += wcnt[v][w];
    const unsigned long long mk = __ballot(myid[v] == m);
    if (myid[v] == m) {
      const int p = wbase + __popcll(mk & ((1ULL << lane) - 1ULL));
      if (p < MAXLIST) list[p] = v * NT + tid;
    }
    for (int w = 0; w < 8; ++w) run += wcnt[v][w];
  }

  // ---- cvt + scatter into fragment-ordered LDS ----
#pragma unroll
  for (int v = 0; v < 16; ++v) {
    const int e4 = v * NT + tid;
    const int r = e4 >> 5;
    const int c0 = (e4 & 31) * 4;
    const int kb = r >> 5;
    const int qq = (r >> 3) & 3;
    const int jj = r & 7;
#pragma unroll
    for (int e = 0; e < 4; ++e) {
      const int c = c0 + e;
      Wfrag[(kb * 8 + (c >> 4)) * FRAGSTRIDE + ((qq * 16) + (c & 15)) * 8 + jj] =
          f2bf(wraw[v][e]);
    }
  }
  __syncthreads();

  // ---- extract this wave's 8 B-fragments (linear ds_read_b128) ----
  bf16x8 bfr[8];
#pragma unroll
  for (int kb = 0; kb < 8; ++kb)
    bfr[kb] = *(const bf16x8*)(Wfrag + (kb * 8 + wv) * FRAGSTRIDE + lane * 8);
  __syncthreads();  // all extractions done; Wfrag region now reusable as As

  const int cnt = (run < MAXLIST) ? run : MAXLIST;
  if (cnt == 0) return;  // uniform exit

  const float bias_c = blut[m * SZ_OUT + col];

  // ---- chunk loop ----
  const int nchunk = (cnt + CHUNK - 1) / CHUNK;
  for (int c = 0; c < nchunk; ++c) {
    const int s0 = c * CHUNK;
    if (c) __syncthreads();  // prior A-frag readers done with As
#pragma unroll
    for (int v = 0; v < 2; ++v) {
      const int e4 = v * NT + tid;
      const int s = e4 >> 6, f4 = e4 & 63;
      int p = s0 + s;
      if (p > cnt - 1) p = cnt - 1;  // pad rows clamp; stores guarded
      const f32x4 a = ((const f32x4*)(inp + (size_t)list[p] * SZ_IN))[f4];
      s16x4 h;
#pragma unroll
      for (int j = 0; j < 4; ++j) h[j] = f2bf(a[j]);
      *(s16x4*)(As + s * LDSK + f4 * 4) = h;
    }
    __syncthreads();

    f32x4 acc = (f32x4){0.f, 0.f, 0.f, 0.f};
#pragma unroll
    for (int kb = 0; kb < 8; ++kb) {
      const bf16x8 afr = *(const bf16x8*)(As + n16 * LDSK + kb * 32 + q * 8);
      acc = __builtin_amdgcn_mfma_f32_16x16x32_bf16(afr, bfr[kb], acc, 0, 0, 0);
    }

#pragma unroll
    for (int r = 0; r < 4; ++r) {
      const int srow = q * 4 + r;
      if (s0 + srow < cnt)
        out[(size_t)list[s0 + srow] * SZ_OUT + col] = acc[r] + bias_c;
    }
  }
}

extern "C" void kernel_launch(void* const* d_in, const int* in_sizes, int n_in,
                              void* d_out, int out_size, void* d_ws, size_t ws_size,
                              hipStream_t stream) {
  const float* inp = (const float*)d_in[0];
  const int* ids = (const int*)d_in[1];
  const float* wlut = (const float*)d_in[2];
  const float* blut = (const float*)d_in[3];
  float* out = (float*)d_out;
  const int B = in_sizes[1];

  // Launch TWICE: second dispatch's marginal cost = true kernel duration
  // (L2-warm), measured as dur13 - dur12. Idempotent -> output identical.
  linmulti_v13<<<dim3(2, NMODELS), NT, 0, stream>>>(inp, ids, wlut, blut, out, B);
  linmulti_v13<<<dim3(2, NMODELS), NT, 0, stream>>>(inp, ids, wlut, blut, out, B);
}

// Round 14
// 95.206 us; speedup vs baseline: 1.0686x; 1.0686x over previous
//
#include <hip/hip_runtime.h>

#define NMODELS 128
#define SZ_IN 256
#define SZ_OUT 256
#define CHUNK 16
#define MAXLIST 192  // Poisson(32)/model; P(cnt>192) ~ 0 (clamped for safety)

typedef __attribute__((ext_vector_type(4))) float f32x4;
typedef __attribute__((ext_vector_type(8))) short bf16x8;

// fp32 -> bf16 RNE (bit pattern)
__device__ __forceinline__ short f2bf(float f) {
  union { float f; unsigned u; } v;
  v.f = f;
  const unsigned r = v.u + 0x7FFFu + ((v.u >> 16) & 1u);
  return (short)(r >> 16);
}

// ONE launch, barrier-minimal. block = (col-quarter cq, model m) -> 512
// blocks = 2/CU; 4 waves; wave owns 16 cols x full K (register B = 8 bf16x8,
// v10-proven strided-dword load pattern).
// Only 2 barriers in the whole kernel (list scan). Chunk loop is fully
// sync-free: A-fragments are built directly from global memory (L2-hot inp),
// no LDS staging, no per-chunk barriers -> each wave is an independent
// pipelined stream of load -> cvt -> MFMA -> store.
// mfma_f32_16x16x32_bf16 layouts (HW-verified R8-R13):
//   A[mrow=lane&15][k=q*8+j], B[k=q*8+j][n=lane&15], D[row=q*4+r][col=lane&15]
__global__ __launch_bounds__(256, 2) void linmulti_v14(
    const float* __restrict__ inp, const int* __restrict__ ids,
    const float* __restrict__ wlut, const float* __restrict__ blut,
    float* __restrict__ out, int B) {
  const int cq = blockIdx.x;  // 0..3
  const int m = blockIdx.y;   // 0..127
  const int tid = threadIdx.x;
  const int lane = tid & 63;
  const int wv = tid >> 6;  // 0..3
  const int q = lane >> 4;
  const int n16 = lane & 15;
  const int col = cq * 64 + wv * 16 + n16;

  __shared__ int list[MAXLIST];
  __shared__ int wcnt[16][4];

  // ---- ids loads (16 coalesced dwords/lane) ----
  int myid[16];
#pragma unroll
  for (int v = 0; v < 16; ++v) {
    const int b = v * 256 + tid;
    myid[v] = (b < B) ? ids[b] : -1;
  }

  // ---- W-slice loads: 64 strided dwords/lane (issue early, cvt later) ----
  const float* __restrict__ Wcol = wlut + (size_t)m * (SZ_IN * SZ_OUT) + col;
  float wraw[8][8];
#pragma unroll
  for (int kb = 0; kb < 8; ++kb)
#pragma unroll
    for (int j = 0; j < 8; ++j)
      wraw[kb][j] = Wcol[(size_t)(kb * 32 + q * 8 + j) * SZ_OUT];

  // ---- deterministic member list (ballot scan, ordered by b) ----
#pragma unroll
  for (int v = 0; v < 16; ++v) {
    const unsigned long long mk = __ballot(myid[v] == m);
    if (lane == 0) wcnt[v][wv] = __popcll(mk);
  }
  __syncthreads();
  int run = 0;
#pragma unroll
  for (int v = 0; v < 16; ++v) {
    int wbase = run;
    for (int w = 0; w < wv; ++w) wbase += wcnt[v][w];
    const unsigned long long mk = __ballot(myid[v] == m);
    if (myid[v] == m) {
      const int p = wbase + __popcll(mk & ((1ULL << lane) - 1ULL));
      if (p < MAXLIST) list[p] = v * 256 + tid;
    }
    for (int w = 0; w < 4; ++w) run += wcnt[v][w];
  }

  // ---- cvt W -> register B-fragments ----
  bf16x8 bfr[8];
#pragma unroll
  for (int kb = 0; kb < 8; ++kb)
#pragma unroll
    for (int j = 0; j < 8; ++j) bfr[kb][j] = f2bf(wraw[kb][j]);

  __syncthreads();  // list complete; LAST barrier in the kernel
  const int cnt = (run < MAXLIST) ? run : MAXLIST;
  if (cnt == 0) return;  // uniform exit

  const float bias_c = blut[m * SZ_OUT + col];

  // ---- sync-free chunk loop: A-fragments direct from global (L2-hot) ----
  const int nchunk = (cnt + CHUNK - 1) / CHUNK;
  for (int c = 0; c < nchunk; ++c) {
    const int s0 = c * CHUNK;
    int p = s0 + n16;
    if (p > cnt - 1) p = cnt - 1;  // pad rows clamp; stores guarded
    const float* __restrict__ Ap = inp + (size_t)list[p] * SZ_IN;

    f32x4 acc = (f32x4){0.f, 0.f, 0.f, 0.f};
#pragma unroll
    for (int kb = 0; kb < 8; ++kb) {
      const f32x4 a0 = *(const f32x4*)(Ap + kb * 32 + q * 8);
      const f32x4 a1 = *(const f32x4*)(Ap + kb * 32 + q * 8 + 4);
      bf16x8 afr;
#pragma unroll
      for (int j = 0; j < 4; ++j) {
        afr[j] = f2bf(a0[j]);
        afr[4 + j] = f2bf(a1[j]);
      }
      acc = __builtin_amdgcn_mfma_f32_16x16x32_bf16(afr, bfr[kb], acc, 0, 0, 0);
    }

#pragma unroll
    for (int r = 0; r < 4; ++r) {
      const int srow = q * 4 + r;
      if (s0 + srow < cnt)
        out[(size_t)list[s0 + srow] * SZ_OUT + col] = acc[r] + bias_c;
    }
  }
}

extern "C" void kernel_launch(void* const* d_in, const int* in_sizes, int n_in,
                              void* d_out, int out_size, void* d_ws, size_t ws_size,
                              hipStream_t stream) {
  const float* inp = (const float*)d_in[0];
  const int* ids = (const int*)d_in[1];
  const float* wlut = (const float*)d_in[2];
  const float* blut = (const float*)d_in[3];
  float* out = (float*)d_out;
  const int B = in_sizes[1];

  linmulti_v14<<<dim3(4, NMODELS), 256, 0, stream>>>(inp, ids, wlut, blut, out, B);
}

// Round 15
// 86.635 us; speedup vs baseline: 1.1743x; 1.0989x over previous
//
#include <hip/hip_runtime.h>

#define NMODELS 128
#define SZ_IN 256
#define SZ_OUT 256
#define CHUNK 16
#define MAXLIST 192   // Poisson(32)/model; P(cnt>192) ~ 0 (clamped for safety)
#define LDSK 264      // bf16 A-row stride: 2-way bank alias (free)
#define NT 512        // 8 waves = 8 n-tiles of the block's 128-col half
#define FRAGSTRIDE 520  // shorts per fragment slot: 512 data + 8 stagger (banks)

typedef __attribute__((ext_vector_type(4))) float f32x4;
typedef __attribute__((ext_vector_type(8))) short bf16x8;
typedef __attribute__((ext_vector_type(4))) short s16x4;

// fp32 -> bf16 RNE (bit pattern)
__device__ __forceinline__ short f2bf(float f) {
  union { float f; unsigned u; } v;
  v.f = f;
  const unsigned r = v.u + 0x7FFFu + ((v.u >> 16) & 1u);
  return (short)(r >> 16);
}

// FINAL (= R12, measured best 87.8 us). ONE launch. block = (col-half ch,
// model m) -> 256 blocks = 1/CU.
// Phase W: coalesced f32x4 row-major stream of W[256k x 128cols], cvt bf16,
//   scatter into fragment-ordered LDS, extract per-wave B-fragments as
//   linear ds_read_b128 -> register-resident B (32 VGPR), full K per wave.
//   W read from HBM exactly once grid-wide (33.5 MB) = 5.3 us/CU hard floor.
// Phase list: deterministic ballot scan ordered by sample index (identical
//   list in both sibling blocks -> no cross-block divergence).
// Phase chunks: stage A[16][256] bf16 to LDS (reusing W buffer), 8 MFMAs
//   per wave per chunk, scatter-store + bias.
// mfma_f32_16x16x32_bf16 layouts (HW-verified R8-R14):
//   A[mrow=lane&15][k=q*8+j], B[k=q*8+j][n=lane&15], D[row=q*4+r][col=lane&15]
__global__ __launch_bounds__(NT, 2) void linmulti_final(
    const float* __restrict__ inp, const int* __restrict__ ids,
    const float* __restrict__ wlut, const float* __restrict__ blut,
    float* __restrict__ out, int B) {
  const int ch = blockIdx.x;  // 0..1 (128-col half)
  const int m = blockIdx.y;   // 0..127
  const int tid = threadIdx.x;
  const int lane = tid & 63;
  const int wv = tid >> 6;   // 0..7 = this wave's n-tile
  const int q = lane >> 4;
  const int n16 = lane & 15;
  const int col = ch * 128 + wv * 16 + n16;

  __shared__ short Wfrag[64 * FRAGSTRIDE];  // 66,560 B; reused as A-tile later
  __shared__ int list[MAXLIST];
  __shared__ int wcnt[8][8];
  short* As = Wfrag;  // A-tile alias (needs 16*LDSK = 4224 shorts)

  // ---- ids loads first (8 coalesced dwords/lane) ----
  int myid[8];
#pragma unroll
  for (int v = 0; v < 8; ++v) {
    const int b = v * NT + tid;
    myid[v] = (b < B) ? ids[b] : -1;
  }

  // ---- W slice, coalesced: 16 f32x4/thread, 512 B row segments ----
  const float* __restrict__ Wb = wlut + (size_t)m * (SZ_IN * SZ_OUT) + ch * 128;
  f32x4 wraw[16];
#pragma unroll
  for (int v = 0; v < 16; ++v) {
    const int e4 = v * NT + tid;       // [0, 8192)
    const int r = e4 >> 5;             // k-row 0..255
    const int c4 = e4 & 31;            // f32x4 within the 128-col row
    wraw[v] = *(const f32x4*)(Wb + (size_t)r * SZ_OUT + c4 * 4);
  }

  // ---- deterministic member list (ballot scan, ordered by b) ----
#pragma unroll
  for (int v = 0; v < 8; ++v) {
    const unsigned long long mk = __ballot(myid[v] == m);
    if (lane == 0) wcnt[v][wv] = __popcll(mk);
  }
  __syncthreads();
  int run = 0;
#pragma unroll
  for (int v = 0; v < 8; ++v) {
    int wbase = run;
    for (int w = 0; w < wv; ++w) wbase += wcnt[v][w];
    const unsigned long long mk = __ballot(myid[v] == m);
    if (myid[v] == m) {
      const int p = wbase + __popcll(mk & ((1ULL << lane) - 1ULL));
      if (p < MAXLIST) list[p] = v * NT + tid;
    }
    for (int w = 0; w < 8; ++w) run += wcnt[v][w];
  }

  // ---- cvt + scatter into fragment-ordered LDS ----
  // element (k-row r, col c) -> frag f = (r>>5)*8 + (c>>4),
  //   slot = ((r>>3 & 3)*16 + (c&15))*8 + (r&7)
#pragma unroll
  for (int v = 0; v < 16; ++v) {
    const int e4 = v * NT + tid;
    const int r = e4 >> 5;
    const int c0 = (e4 & 31) * 4;
    const int kb = r >> 5;
    const int qq = (r >> 3) & 3;
    const int jj = r & 7;
#pragma unroll
    for (int e = 0; e < 4; ++e) {
      const int c = c0 + e;
      Wfrag[(kb * 8 + (c >> 4)) * FRAGSTRIDE + ((qq * 16) + (c & 15)) * 8 + jj] =
          f2bf(wraw[v][e]);
    }
  }
  __syncthreads();

  // ---- extract this wave's 8 B-fragments (linear ds_read_b128) ----
  bf16x8 bfr[8];
#pragma unroll
  for (int kb = 0; kb < 8; ++kb)
    bfr[kb] = *(const bf16x8*)(Wfrag + (kb * 8 + wv) * FRAGSTRIDE + lane * 8);
  __syncthreads();  // all extractions done; Wfrag region now reusable as As

  const int cnt = (run < MAXLIST) ? run : MAXLIST;
  if (cnt == 0) return;  // uniform exit

  const float bias_c = blut[m * SZ_OUT + col];

  // ---- chunk loop ----
  const int nchunk = (cnt + CHUNK - 1) / CHUNK;
  for (int c = 0; c < nchunk; ++c) {
    const int s0 = c * CHUNK;
    if (c) __syncthreads();  // prior A-frag readers done with As
    // stage A: 16 rows x 256 floats = 1024 f32x4, 2/thread, cvt to bf16
#pragma unroll
    for (int v = 0; v < 2; ++v) {
      const int e4 = v * NT + tid;
      const int s = e4 >> 6, f4 = e4 & 63;
      int p = s0 + s;
      if (p > cnt - 1) p = cnt - 1;  // pad rows clamp; stores guarded
      const f32x4 a = ((const f32x4*)(inp + (size_t)list[p] * SZ_IN))[f4];
      s16x4 h;
#pragma unroll
      for (int j = 0; j < 4; ++j) h[j] = f2bf(a[j]);
      *(s16x4*)(As + s * LDSK + f4 * 4) = h;
    }
    __syncthreads();

    f32x4 acc = (f32x4){0.f, 0.f, 0.f, 0.f};
#pragma unroll
    for (int kb = 0; kb < 8; ++kb) {
      const bf16x8 afr = *(const bf16x8*)(As + n16 * LDSK + kb * 32 + q * 8);
      acc = __builtin_amdgcn_mfma_f32_16x16x32_bf16(afr, bfr[kb], acc, 0, 0, 0);
    }

#pragma unroll
    for (int r = 0; r < 4; ++r) {
      const int srow = q * 4 + r;
      if (s0 + srow < cnt)
        out[(size_t)list[s0 + srow] * SZ_OUT + col] = acc[r] + bias_c;
    }
  }
}

extern "C" void kernel_launch(void* const* d_in, const int* in_sizes, int n_in,
                              void* d_out, int out_size, void* d_ws, size_t ws_size,
                              hipStream_t stream) {
  const float* inp = (const float*)d_in[0];
  const int* ids = (const int*)d_in[1];
  const float* wlut = (const float*)d_in[2];
  const float* blut = (const float*)d_in[3];
  float* out = (float*)d_out;
  const int B = in_sizes[1];

  linmulti_final<<<dim3(2, NMODELS), NT, 0, stream>>>(inp, ids, wlut, blut, out, B);
}